// Round 3
// baseline (2488.349 us; speedup 1.0000x reference)
//
#include <hip/hip_runtime.h>
#include <hip/hip_bf16.h>

#define HN  128   // feature dim
#define NPG 32    // nodes per graph

typedef float f4 __attribute__((ext_vector_type(4)));

__global__ __launch_bounds__(256) void gib_main(
    const float* __restrict__ x,  const float* __restrict__ W1,
    const float* __restrict__ b1, const float* __restrict__ W2,
    const float* __restrict__ b2, const float* __restrict__ gn,
    const float* __restrict__ un, const int* __restrict__ ei,
    float* __restrict__ out, float* __restrict__ ws,
    int G, long N, long E, int epg)
{
  const int g = blockIdx.x;
  const int t = threadIdx.x;
  const long nb = (long)g * NPG;
  const float* xg = x + nb * HN;
  const float* ug = un + nb * HN;

  __shared__ float s_mean[HN], s_std[HN], s_iv[HN];
  __shared__ float s_pA[2][HN], s_pB[2][HN];
  __shared__ float s_a0[NPG], s_a1[NPG], s_lp[NPG], s_ln[NPG];
  __shared__ float s_zred[4][8][4][2];
  __shared__ float s_sr2[2];
  __shared__ float s_t2[4];
  __shared__ float s_adj[4][4];
  __shared__ float s_SLN, s_SLN2, s_pres;

  // ---------- Pass 1: per-feature stats + graph_emb ----------
  {
    const int f = t & (HN - 1);
    const int half = t >> 7;
    float s1 = 0.f, s2 = 0.f;
    #pragma unroll
    for (int i = 0; i < 16; ++i) {
      float v = xg[(half * 16 + i) * HN + f];
      s1 += v; s2 += v * v;
    }
    s_pA[half][f] = s1; s_pB[half][f] = s2;
  }
  __syncthreads();
  if (t < HN) {
    float s1 = s_pA[0][t] + s_pA[1][t];
    float s2 = s_pB[0][t] + s_pB[1][t];
    float mean = s1 * (1.0f / NPG);
    float var  = (s2 - s1 * mean) * (1.0f / (NPG - 1));
    var = fmaxf(var, 0.f);
    float sd  = sqrtf(var);
    float inv = 1.0f / (sd + 1e-7f);
    s_mean[t] = mean; s_std[t] = sd; s_iv[t] = inv * inv;
    float r  = sd * inv;
    float r2 = r * r;
    #pragma unroll
    for (int m = 1; m < 64; m <<= 1) r2 += __shfl_xor(r2, m, 64);
    if ((t & 63) == 0) s_sr2[t >> 6] = r2;
    out[(long)g * HN + t] = s1;   // graph_emb (f32)
  }
  __syncthreads();

  // ---------- Pass 2: MLP (x@W1 -> tanh -> @W2), hidden stays in registers ----------
  const int ng = t & 7;            // node group: nodes ng, ng+8, ng+16, ng+24
  const int h0 = (t >> 3) << 2;    // 4 hidden columns h0..h0+3
  float acc[4][4];
  #pragma unroll
  for (int j = 0; j < 4; ++j) {
    float b = b1[h0 + j];
    acc[0][j] = b; acc[1][j] = b; acc[2][j] = b; acc[3][j] = b;
  }
  #pragma unroll 2
  for (int kc = 0; kc < HN / 4; ++kc) {
    const int k = kc * 4;
    f4 w0 = *(const f4*)(W1 + (k + 0) * HN + h0);
    f4 w1 = *(const f4*)(W1 + (k + 1) * HN + h0);
    f4 w2 = *(const f4*)(W1 + (k + 2) * HN + h0);
    f4 w3 = *(const f4*)(W1 + (k + 3) * HN + h0);
    #pragma unroll
    for (int i = 0; i < 4; ++i) {
      f4 xv = *(const f4*)(xg + (ng + 8 * i) * HN + k);
      #pragma unroll
      for (int j = 0; j < 4; ++j) {
        acc[i][j] = fmaf(xv[0], w0[j], acc[i][j]);
        acc[i][j] = fmaf(xv[1], w1[j], acc[i][j]);
        acc[i][j] = fmaf(xv[2], w2[j], acc[i][j]);
        acc[i][j] = fmaf(xv[3], w3[j], acc[i][j]);
      }
    }
  }
  float zp[4][2];
  {
    float w2c0[4], w2c1[4];
    #pragma unroll
    for (int j = 0; j < 4; ++j) {
      w2c0[j] = W2[(h0 + j) * 2 + 0];
      w2c1[j] = W2[(h0 + j) * 2 + 1];
    }
    #pragma unroll
    for (int i = 0; i < 4; ++i) {
      float z0 = 0.f, z1 = 0.f;
      #pragma unroll
      for (int j = 0; j < 4; ++j) {
        float hv = tanhf(acc[i][j]);
        z0 = fmaf(hv, w2c0[j], z0);
        z1 = fmaf(hv, w2c1[j], z1);
      }
      zp[i][0] = z0; zp[i][1] = z1;
    }
  }
  #pragma unroll
  for (int m = 8; m <= 32; m <<= 1)
    #pragma unroll
    for (int i = 0; i < 4; ++i) {
      zp[i][0] += __shfl_xor(zp[i][0], m, 64);
      zp[i][1] += __shfl_xor(zp[i][1], m, 64);
    }
  if ((t & 63) < 8) {
    const int w = t >> 6;
    #pragma unroll
    for (int i = 0; i < 4; ++i) {
      s_zred[w][ng][i][0] = zp[i][0];
      s_zred[w][ng][i][1] = zp[i][1];
    }
  }
  __syncthreads();

  // ---------- softmax / gumbel per node ----------
  if (t < NPG) {
    const int n = t;
    float z0 = b2[0], z1 = b2[1];
    #pragma unroll
    for (int w = 0; w < 4; ++w) {
      z0 += s_zred[w][n & 7][n >> 3][0];
      z1 += s_zred[w][n & 7][n >> 3][1];
    }
    float zm = fmaxf(z0, z1);
    float e0 = expf(z0 - zm), e1 = expf(z1 - zm);
    float es = e0 + e1;
    float a0 = e0 / es, a1 = e1 / es;
    float q0 = a0 + gn[(nb + n) * 2 + 0];
    float q1 = a1 + gn[(nb + n) * 2 + 1];
    float qm = fmaxf(q0, q1);
    float E0 = expf(q0 - qm), E1 = expf(q1 - qm);
    float Es = E0 + E1;
    float lp = E0 / Es, lneg = E1 / Es;
    s_a0[n] = a0; s_a1[n] = a1; s_lp[n] = lp; s_ln[n] = lneg;
    out[2L * G * HN + nb + n] = (lp > 0.5f) ? 1.0f : 0.0f;  // active (f32 0/1)
    float v1 = lneg, v2 = lneg * lneg, v3 = (a0 > 0.5f) ? 1.f : 0.f;
    #pragma unroll
    for (int m = 1; m < 32; m <<= 1) {
      v1 += __shfl_xor(v1, m, 64);
      v2 += __shfl_xor(v2, m, 64);
      v3 += __shfl_xor(v3, m, 64);
    }
    if (t == 0) { s_SLN = v1; s_SLN2 = v2; s_pres = v3; }
  }
  __syncthreads();

  // ---------- Pass 3: T2 = sum_n lam_pos^2 * sum_f (x-mean)^2/(std+eps)^2 ----------
  {
    const int n = t >> 3, fq = t & 7;
    float s = 0.f;
    #pragma unroll
    for (int c = 0; c < 4; ++c) {
      f4 xv = *(const f4*)(xg + n * HN + fq * 16 + c * 4);
      #pragma unroll
      for (int i = 0; i < 4; ++i) {
        const int f = fq * 16 + c * 4 + i;
        float d = xv[i] - s_mean[f];
        s = fmaf(d * d, s_iv[f], s);
      }
    }
    #pragma unroll
    for (int m = 1; m <= 4; m <<= 1) s += __shfl_xor(s, m, 64);
    float v = (fq == 0) ? s_lp[n] * s_lp[n] * s : 0.f;
    #pragma unroll
    for (int m = 8; m <= 32; m <<= 1) v += __shfl_xor(v, m, 64);
    if ((t & 63) == 0) s_t2[t >> 6] = v;
  }

  // ---------- Pass 4: noisy_emb ----------
  {
    const int f = t & (HN - 1), half = t >> 7;
    float A = 0.f, B = 0.f;
    #pragma unroll
    for (int i = 0; i < 16; ++i) {
      const int n = half * 16 + i;
      A = fmaf(s_lp[n], xg[n * HN + f], A);
      B = fmaf(s_ln[n], ug[n * HN + f], B);
    }
    s_pA[half][f] = A; s_pB[half][f] = B;
  }
  __syncthreads();
  if (t < HN) {
    float A = s_pA[0][t] + s_pA[1][t];
    float B = s_pB[0][t] + s_pB[1][t];
    float ne = A + s_mean[t] * s_SLN + s_std[t] * B;
    out[(long)G * HN + (long)g * HN + t] = ne;  // noisy_emb (f32)
  }

  // ---------- Pass 5: edges -> pos_penalty; write per-graph scalars ----------
  {
    float c00 = 0.f, c01 = 0.f, c10 = 0.f, c11 = 0.f;
    for (int e = t; e < epg; e += 256) {
      const long eb = (long)g * epg + e;
      int src = ei[eb] - g * NPG;
      int dst = ei[E + eb] - g * NPG;
      float as0 = s_a0[src], as1 = s_a1[src];
      float ad0 = s_a0[dst], ad1 = s_a1[dst];
      c00 = fmaf(as0, ad0, c00);
      c01 = fmaf(as0, ad1, c01);
      c10 = fmaf(as1, ad0, c10);
      c11 = fmaf(as1, ad1, c11);
    }
    #pragma unroll
    for (int m = 1; m < 64; m <<= 1) {
      c00 += __shfl_xor(c00, m, 64);
      c01 += __shfl_xor(c01, m, 64);
      c10 += __shfl_xor(c10, m, 64);
      c11 += __shfl_xor(c11, m, 64);
    }
    if ((t & 63) == 0) {
      float* p = s_adj[t >> 6];
      p[0] = c00; p[1] = c01; p[2] = c10; p[3] = c11;
    }
  }
  __syncthreads();
  if (t == 0) {
    float a00 = s_adj[0][0] + s_adj[1][0] + s_adj[2][0] + s_adj[3][0];
    float a01 = s_adj[0][1] + s_adj[1][1] + s_adj[2][1] + s_adj[3][1];
    float a10 = s_adj[0][2] + s_adj[1][2] + s_adj[2][2] + s_adj[3][2];
    float a11 = s_adj[0][3] + s_adj[1][3] + s_adj[2][3] + s_adj[3][3];
    float d0 = a00 / fmaxf(fabsf(a00) + fabsf(a01), 1e-12f);
    float d1 = a11 / fmaxf(fabsf(a10) + fabsf(a11), 1e-12f);
    float pen = 0.5f * ((d0 - 1.f) * (d0 - 1.f) + (d1 - 1.f) * (d1 - 1.f));
    float t2  = s_t2[0] + s_t2[1] + s_t2[2] + s_t2[3];
    float sr2 = s_sr2[0] + s_sr2[1];
    float kl  = (0.5f * s_SLN2 * sr2 + (float)NPG * t2) / (float)(NPG * HN);
    ws[g]                 = kl;
    ws[(size_t)G + g]     = pen;
    ws[2 * (size_t)G + g] = s_pres * (1.0f / NPG);
  }
}

// deterministic fixed-order reduction of the 3 per-graph scalar arrays
__global__ __launch_bounds__(256) void gib_final(const float* __restrict__ ws,
                                                 float* __restrict__ out,
                                                 int G, long base)
{
  __shared__ float red[256];
  const int t = threadIdx.x;
  const int srcArr[3] = {1, 0, 2};  // out order: pos_penalty, kl_loss, preserve_rate
  for (int o = 0; o < 3; ++o) {
    const float* p = ws + (size_t)srcArr[o] * G;
    float s = 0.f;
    for (int i = t; i < G; i += 256) s += p[i];
    red[t] = s;
    __syncthreads();
    for (int st = 128; st > 0; st >>= 1) {
      if (t < st) red[t] += red[t + st];
      __syncthreads();
    }
    if (t == 0) out[base + o] = red[0] / (float)G;
    __syncthreads();
  }
}

extern "C" void kernel_launch(void* const* d_in, const int* in_sizes, int n_in,
                              void* d_out, int out_size, void* d_ws, size_t ws_size,
                              hipStream_t stream)
{
  const float* x  = (const float*)d_in[0];
  const float* W1 = (const float*)d_in[1];
  const float* b1 = (const float*)d_in[2];
  const float* W2 = (const float*)d_in[3];
  const float* b2 = (const float*)d_in[4];
  const float* gn = (const float*)d_in[5];
  const float* un = (const float*)d_in[6];
  const int*   ei = (const int*)d_in[7];
  float* out = (float*)d_out;
  float* ws  = (float*)d_ws;

  const long N = (long)in_sizes[0] / HN;
  const int  G = (int)(N / NPG);
  const long E = (long)in_sizes[7] / 2;
  const int epg = (int)(E / G);

  hipLaunchKernelGGL(gib_main, dim3(G), dim3(256), 0, stream,
                     x, W1, b1, W2, b2, gn, un, ei, out, ws, G, N, E, epg);
  const long base = 2L * (long)G * HN + N;
  hipLaunchKernelGGL(gib_final, dim3(1), dim3(256), 0, stream, ws, out, G, base);
}

// Round 4
// 1254.843 us; speedup vs baseline: 1.9830x; 1.9830x over previous
//
#include <hip/hip_runtime.h>

#define HN  128   // feature dim
#define NPG 32    // nodes per graph
#define GPB 16    // graphs per block
#define NT  512   // threads per block (8 waves)

typedef float f4 __attribute__((ext_vector_type(4)));
typedef float f2 __attribute__((ext_vector_type(2)));

// physical chunk slot for logical 16B-chunk c of node n (bank-conflict swizzle)
__device__ __forceinline__ int xch(int n, int c) { return c ^ (n & 7); }

__global__ __launch_bounds__(NT) void gib_main(
    const float* __restrict__ x,  const float* __restrict__ W1,
    const float* __restrict__ b1, const float* __restrict__ W2,
    const float* __restrict__ b2, const float* __restrict__ gn,
    const float* __restrict__ un, const int* __restrict__ ei,
    float* __restrict__ out, float* __restrict__ ws,
    int G, long E, int epg)
{
  const int t  = threadIdx.x;
  const int ng = t & 7;          // node group: nodes ng, ng+8, ng+16, ng+24
  const int hp = t >> 3;         // h-pair / f-pair index 0..63
  const int w  = t >> 6;         // wave 0..7
  const int hl = (t >> 3) & 7;   // hp-local within wave

  __shared__ __align__(16) float W1s[HN * HN];          // 64 KB
  __shared__ __align__(16) float xs[2][NPG * HN];       // 2 x 16 KB, swizzled chunks
  __shared__ float zred[8][8][4][2];                    // [wave][ng][i][c]
  __shared__ float s_mean[HN], s_std[HN], s_iv[HN];
  __shared__ float s_a0[NPG], s_a1[NPG], s_lp[NPG], s_ln[NPG];
  __shared__ float t3p[8];      // per-wave T2 partial
  __shared__ float sr2p[8];     // per-wave sum (std/(std+eps))^2 partial
  __shared__ float adjp[2][4];  // per-wave adj partials (waves 0,1)
  __shared__ float s_scal[3];   // SLN, SLN2, pres

  const long GL = (long)G * HN;
  const long Nn = (long)G * NPG;

  int g0 = blockIdx.x * GPB;
  int gcnt = min(GPB, G - g0);
  if (gcnt <= 0) return;

  // ---- prologue: stage W1 (linear) and x tile of first graph (swizzled) ----
  #pragma unroll
  for (int r = 0; r < (HN * HN / 4) / NT; ++r) {
    int s = r * NT + t;
    *(f4*)&W1s[s * 4] = *(const f4*)(W1 + s * 4);
  }
  {
    const float* xg = x + (long)g0 * NPG * HN;
    #pragma unroll
    for (int r = 0; r < 2; ++r) {
      int s = r * NT + t;                 // physical chunk slot 0..1023
      int n = s >> 5, p = s & 31, c = xch(n, p);  // logical chunk (involution)
      *(f4*)&xs[0][s * 4] = *(const f4*)(xg + n * HN + c * 4);
    }
  }
  const f2 b1v = *(const f2*)(b1 + 2 * hp);
  const f4 w2v = *(const f4*)(W2 + 4 * hp);   // [W2[2hp][0], W2[2hp][1], W2[2hp+1][0], W2[2hp+1][1]]
  const float b20 = b2[0], b21 = b2[1];
  __syncthreads();

  for (int gi = 0; gi < gcnt; ++gi) {
    const int  g  = g0 + gi;
    const int  b  = gi & 1;
    const long nb = (long)g * NPG;

    // ---- (A) issue global prefetches (consumed much later; latency hidden) ----
    f4 nx0 = {0,0,0,0}, nx1 = {0,0,0,0};
    const bool havenext = (gi + 1 < gcnt);
    if (havenext) {
      const float* xg = x + (nb + NPG) * HN;
      { int s = t;      int n = s >> 5, p = s & 31, c = xch(n, p);
        nx0 = *(const f4*)(xg + n * HN + c * 4); }
      { int s = NT + t; int n = s >> 5, p = s & 31, c = xch(n, p);
        nx1 = *(const f4*)(xg + n * HN + c * 4); }
    }
    f2 unr[4];
    {
      const float* ug = un + nb * HN;
      #pragma unroll
      for (int i = 0; i < 4; ++i)
        unr[i] = *(const f2*)(ug + (ng + 8 * i) * HN + 2 * hp);
    }
    f2 gnr = {0.f, 0.f};
    if (t < NPG) gnr = *(const f2*)(gn + (nb + t) * 2);
    int esrc = 0, edst = 0;
    if (t < epg) {
      long eb = (long)g * epg + t;
      esrc = ei[eb] - g * NPG;
      edst = ei[E + eb] - g * NPG;
    }

    // ---- (B) pass1: per-feature stats + graph_emb ----
    {
      float s10 = 0.f, s11 = 0.f, s20 = 0.f, s21 = 0.f;
      #pragma unroll
      for (int i = 0; i < 4; ++i) {
        int n = ng + 8 * i;
        f2 v = *(const f2*)&xs[b][n * HN + xch(n, hp >> 1) * 4 + (hp & 1) * 2];
        s10 += v[0]; s11 += v[1];
        s20 = fmaf(v[0], v[0], s20); s21 = fmaf(v[1], v[1], s21);
      }
      #pragma unroll
      for (int m = 1; m <= 4; m <<= 1) {
        s10 += __shfl_xor(s10, m, 64); s11 += __shfl_xor(s11, m, 64);
        s20 += __shfl_xor(s20, m, 64); s21 += __shfl_xor(s21, m, 64);
      }
      if (ng == 0) {
        float mean0 = s10 * (1.f / NPG), mean1 = s11 * (1.f / NPG);
        float var0 = fmaxf((s20 - s10 * mean0) * (1.f / (NPG - 1)), 0.f);
        float var1 = fmaxf((s21 - s11 * mean1) * (1.f / (NPG - 1)), 0.f);
        float sd0 = sqrtf(var0), sd1 = sqrtf(var1);
        float inv0 = 1.f / (sd0 + 1e-7f), inv1 = 1.f / (sd1 + 1e-7f);
        s_mean[2 * hp] = mean0;  s_mean[2 * hp + 1] = mean1;
        s_std [2 * hp] = sd0;    s_std [2 * hp + 1] = sd1;
        s_iv  [2 * hp] = inv0 * inv0; s_iv[2 * hp + 1] = inv1 * inv1;
        out[(long)g * HN + 2 * hp]     = s10;   // graph_emb
        out[(long)g * HN + 2 * hp + 1] = s11;
        float r0 = sd0 * inv0, r1 = sd1 * inv1;
        float r2 = r0 * r0 + r1 * r1;
        #pragma unroll
        for (int m = 8; m <= 32; m <<= 1) r2 += __shfl_xor(r2, m, 64);
        if (hl == 0) sr2p[w] = r2;
      }
    }

    // ---- (C) MLP: hidden[n][2hp..2hp+1] for 4 nodes, all operands in LDS ----
    float acc[4][2];
    #pragma unroll
    for (int i = 0; i < 4; ++i) { acc[i][0] = b1v[0]; acc[i][1] = b1v[1]; }
    #pragma unroll 4
    for (int kc = 0; kc < HN / 4; ++kc) {
      f2 w1r0 = *(const f2*)&W1s[(4 * kc + 0) * HN + 2 * hp];
      f2 w1r1 = *(const f2*)&W1s[(4 * kc + 1) * HN + 2 * hp];
      f2 w1r2 = *(const f2*)&W1s[(4 * kc + 2) * HN + 2 * hp];
      f2 w1r3 = *(const f2*)&W1s[(4 * kc + 3) * HN + 2 * hp];
      #pragma unroll
      for (int i = 0; i < 4; ++i) {
        int n = ng + 8 * i;
        f4 xv = *(const f4*)&xs[b][n * HN + xch(n, kc) * 4];
        acc[i][0] = fmaf(xv[0], w1r0[0], acc[i][0]); acc[i][1] = fmaf(xv[0], w1r0[1], acc[i][1]);
        acc[i][0] = fmaf(xv[1], w1r1[0], acc[i][0]); acc[i][1] = fmaf(xv[1], w1r1[1], acc[i][1]);
        acc[i][0] = fmaf(xv[2], w1r2[0], acc[i][0]); acc[i][1] = fmaf(xv[2], w1r2[1], acc[i][1]);
        acc[i][0] = fmaf(xv[3], w1r3[0], acc[i][0]); acc[i][1] = fmaf(xv[3], w1r3[1], acc[i][1]);
      }
    }
    #pragma unroll
    for (int i = 0; i < 4; ++i) {
      float h0 = tanhf(acc[i][0]), h1 = tanhf(acc[i][1]);
      float z0 = fmaf(h0, w2v[0], h1 * w2v[2]);
      float z1 = fmaf(h0, w2v[1], h1 * w2v[3]);
      #pragma unroll
      for (int m = 8; m <= 32; m <<= 1) {
        z0 += __shfl_xor(z0, m, 64); z1 += __shfl_xor(z1, m, 64);
      }
      if (hl == 0) { zred[w][ng][i][0] = z0; zred[w][ng][i][1] = z1; }
    }
    __syncthreads();   // (D)

    // ---- (E) softmax/gumbel per node (t<32); stage next x tile (all threads) ----
    if (t < NPG) {
      float z0 = b20, z1 = b21;
      #pragma unroll
      for (int wi = 0; wi < 8; ++wi) {
        z0 += zred[wi][t & 7][t >> 3][0];
        z1 += zred[wi][t & 7][t >> 3][1];
      }
      float zm = fmaxf(z0, z1);
      float e0 = expf(z0 - zm), e1 = expf(z1 - zm);
      float a0 = e0 / (e0 + e1), a1 = 1.f - a0;
      float q0 = a0 + gnr[0], q1 = a1 + gnr[1];
      float qm = fmaxf(q0, q1);
      float E0 = expf(q0 - qm), E1 = expf(q1 - qm);
      float lp = E0 / (E0 + E1), ln = 1.f - lp;
      s_a0[t] = a0; s_a1[t] = a1; s_lp[t] = lp; s_ln[t] = ln;
      out[2 * GL + nb + t] = (lp > 0.5f) ? 1.0f : 0.0f;   // active
      float v1 = ln, v2 = ln * ln, v3 = (a0 > 0.5f) ? 1.f : 0.f;
      #pragma unroll
      for (int m = 1; m < 32; m <<= 1) {
        v1 += __shfl_xor(v1, m, 64);
        v2 += __shfl_xor(v2, m, 64);
        v3 += __shfl_xor(v3, m, 64);
      }
      if (t == 0) { s_scal[0] = v1; s_scal[1] = v2; s_scal[2] = v3; }
    }
    if (havenext) {   // write prefetched tile into the other buffer
      *(f4*)&xs[b ^ 1][t * 4]        = nx0;
      *(f4*)&xs[b ^ 1][(NT + t) * 4] = nx1;
    }
    __syncthreads();   // (E-end)

    // ---- (F) pass3 (T2) + pass4 (noisy_emb) ----
    f2 mu = *(const f2*)&s_mean[2 * hp];
    {
      f2 iv = *(const f2*)&s_iv[2 * hp];
      float tv = 0.f;
      #pragma unroll
      for (int i = 0; i < 4; ++i) {
        int n = ng + 8 * i;
        f2 v = *(const f2*)&xs[b][n * HN + xch(n, hp >> 1) * 4 + (hp & 1) * 2];
        float d0 = v[0] - mu[0], d1 = v[1] - mu[1];
        float sE = fmaf(d0 * d0, iv[0], d1 * d1 * iv[1]);
        float lpn = s_lp[n];
        tv = fmaf(lpn * lpn, sE, tv);
      }
      #pragma unroll
      for (int m = 1; m < 64; m <<= 1) tv += __shfl_xor(tv, m, 64);
      if ((t & 63) == 0) t3p[w] = tv;
    }
    {
      float A0 = 0.f, A1 = 0.f, B0 = 0.f, B1 = 0.f;
      #pragma unroll
      for (int i = 0; i < 4; ++i) {
        int n = ng + 8 * i;
        f2 v = *(const f2*)&xs[b][n * HN + xch(n, hp >> 1) * 4 + (hp & 1) * 2];
        float lpn = s_lp[n], lnn = s_ln[n];
        A0 = fmaf(lpn, v[0], A0); A1 = fmaf(lpn, v[1], A1);
        B0 = fmaf(lnn, unr[i][0], B0); B1 = fmaf(lnn, unr[i][1], B1);
      }
      #pragma unroll
      for (int m = 1; m <= 4; m <<= 1) {
        A0 += __shfl_xor(A0, m, 64); A1 += __shfl_xor(A1, m, 64);
        B0 += __shfl_xor(B0, m, 64); B1 += __shfl_xor(B1, m, 64);
      }
      if (ng == 0) {
        float SLN = s_scal[0];
        f2 sd = *(const f2*)&s_std[2 * hp];
        out[GL + (long)g * HN + 2 * hp]     = fmaf(mu[0], SLN, A0) + sd[0] * B0;
        out[GL + (long)g * HN + 2 * hp + 1] = fmaf(mu[1], SLN, A1) + sd[1] * B1;
      }
    }

    // ---- (G) pass5: edges -> 2x2 adjacency; finalize scalars ----
    {
      float c00 = 0.f, c01 = 0.f, c10 = 0.f, c11 = 0.f;
      if (t < epg) {
        float as0 = s_a0[esrc], as1 = s_a1[esrc];
        float ad0 = s_a0[edst], ad1 = s_a1[edst];
        c00 = as0 * ad0; c01 = as0 * ad1; c10 = as1 * ad0; c11 = as1 * ad1;
      }
      for (int e = NT + t; e < epg; e += NT) {   // generic fallback (unused at epg=128)
        long eb = (long)g * epg + e;
        int s2 = ei[eb] - g * NPG, d2 = ei[E + eb] - g * NPG;
        float as0 = s_a0[s2], as1 = s_a1[s2];
        float ad0 = s_a0[d2], ad1 = s_a1[d2];
        c00 = fmaf(as0, ad0, c00); c01 = fmaf(as0, ad1, c01);
        c10 = fmaf(as1, ad0, c10); c11 = fmaf(as1, ad1, c11);
      }
      #pragma unroll
      for (int m = 1; m < 64; m <<= 1) {
        c00 += __shfl_xor(c00, m, 64); c01 += __shfl_xor(c01, m, 64);
        c10 += __shfl_xor(c10, m, 64); c11 += __shfl_xor(c11, m, 64);
      }
      if ((t & 63) == 0 && w < 2) {
        adjp[w][0] = c00; adjp[w][1] = c01; adjp[w][2] = c10; adjp[w][3] = c11;
      }
    }
    __syncthreads();   // (G-mid)
    if (t < 8) {
      float v = t3p[t], r = sr2p[t];
      #pragma unroll
      for (int m = 1; m <= 4; m <<= 1) {
        v += __shfl_xor(v, m, 64); r += __shfl_xor(r, m, 64);
      }
      if (t == 0) {
        float a00 = adjp[0][0] + adjp[1][0];
        float a01 = adjp[0][1] + adjp[1][1];
        float a10 = adjp[0][2] + adjp[1][2];
        float a11 = adjp[0][3] + adjp[1][3];
        float d0 = a00 / fmaxf(fabsf(a00) + fabsf(a01), 1e-12f);
        float d1 = a11 / fmaxf(fabsf(a10) + fabsf(a11), 1e-12f);
        float pen = 0.5f * ((d0 - 1.f) * (d0 - 1.f) + (d1 - 1.f) * (d1 - 1.f));
        float kl  = (0.5f * s_scal[1] * r + (float)NPG * v) / (float)(NPG * HN);
        ws[g]                 = kl;
        ws[(size_t)G + g]     = pen;
        ws[2 * (size_t)G + g] = s_scal[2] * (1.0f / NPG);
      }
    }
  }
}

// deterministic fixed-order reduction of the 3 per-graph scalar arrays
__global__ __launch_bounds__(256) void gib_final(const float* __restrict__ ws,
                                                 float* __restrict__ out,
                                                 int G, long base)
{
  __shared__ float red[256];
  const int t = threadIdx.x;
  const int srcArr[3] = {1, 0, 2};  // out order: pos_penalty, kl_loss, preserve_rate
  for (int o = 0; o < 3; ++o) {
    const float* p = ws + (size_t)srcArr[o] * G;
    float s = 0.f;
    for (int i = t; i < G; i += 256) s += p[i];
    red[t] = s;
    __syncthreads();
    for (int st = 128; st > 0; st >>= 1) {
      if (t < st) red[t] += red[t + st];
      __syncthreads();
    }
    if (t == 0) out[base + o] = red[0] / (float)G;
    __syncthreads();
  }
}

extern "C" void kernel_launch(void* const* d_in, const int* in_sizes, int n_in,
                              void* d_out, int out_size, void* d_ws, size_t ws_size,
                              hipStream_t stream)
{
  const float* x  = (const float*)d_in[0];
  const float* W1 = (const float*)d_in[1];
  const float* b1 = (const float*)d_in[2];
  const float* W2 = (const float*)d_in[3];
  const float* b2 = (const float*)d_in[4];
  const float* gn = (const float*)d_in[5];
  const float* un = (const float*)d_in[6];
  const int*   ei = (const int*)d_in[7];
  float* out = (float*)d_out;
  float* ws  = (float*)d_ws;

  const long N = (long)in_sizes[0] / HN;
  const int  G = (int)(N / NPG);
  const long E = (long)in_sizes[7] / 2;
  const int epg = (int)(E / G);

  const int nblocks = (G + GPB - 1) / GPB;
  hipLaunchKernelGGL(gib_main, dim3(nblocks), dim3(NT), 0, stream,
                     x, W1, b1, W2, b2, gn, un, ei, out, ws, G, E, epg);
  const long base = 2L * (long)G * HN + N;
  hipLaunchKernelGGL(gib_final, dim3(1), dim3(256), 0, stream, ws, out, G, base);
}

// Round 5
// 750.839 us; speedup vs baseline: 3.3141x; 1.6713x over previous
//
#include <hip/hip_runtime.h>

#define HN   128
#define NPG  32
#define GP4  4            // graphs per set (concurrent)
#define NT   512
#define SX   132          // padded floats per node row (528 B, 16B-aligned)
#define TILE (NPG * SX)   // 4224 floats

typedef float f4 __attribute__((ext_vector_type(4)));
typedef float f2 __attribute__((ext_vector_type(2)));

__global__ __launch_bounds__(NT, 2) void gib_main(
    const float* __restrict__ x,  const float* __restrict__ W1,
    const float* __restrict__ b1, const float* __restrict__ W2,
    const float* __restrict__ b2, const float* __restrict__ gn,
    const float* __restrict__ un, const int* __restrict__ ei,
    float* __restrict__ out, float* __restrict__ ws,
    int G, long E, int epg, int spb)
{
  const int t    = threadIdx.x;
  const int p    = t >> 7;        // graph-in-set 0..3
  const int lo   = t & 127;
  const int ng   = lo & 7;        // node group (nodes ng, ng+8, ng+16, ng+24)
  const int cg   = lo >> 3;       // col group 0..15 (cols 8cg..8cg+7)
  const int wv   = t >> 6;        // wave 0..7
  const int lid  = t & 63;
  const int half = lo >> 6;       // which wave within the graph's pair
  const int fp   = lo & 63;       // feature pair

  __shared__ __align__(16) float W1s[HN * HN];     // chunk-deinterleaved rows
  __shared__ __align__(16) float xs[GP4 * TILE];   // padded x tiles
  __shared__ float zred[GP4][2][8][4][2];
  __shared__ float pA[GP4][2][HN], pB[GP4][2][HN];
  __shared__ float s_mean[GP4][HN], s_std[GP4][HN], s_iv[GP4][HN];
  __shared__ float s_a0[GP4][NPG], s_a1[GP4][NPG], s_lp[GP4][NPG], s_ln[GP4][NPG];
  __shared__ float t2p[GP4][2], sr2p[GP4], adjp[GP4][2][4], s_scal[GP4][3];

  const long GL = (long)G * HN;
  const int  g0 = blockIdx.x * (GP4 * spb);

  // persistent small params
  const f4 b1a = *(const f4*)(b1 + 8 * cg);
  const f4 b1b = *(const f4*)(b1 + 8 * cg + 4);
  float w2l[16];
  #pragma unroll
  for (int u = 0; u < 4; ++u) {
    f4 v = *(const f4*)(W2 + 16 * cg + 4 * u);
    w2l[4*u+0] = v[0]; w2l[4*u+1] = v[1]; w2l[4*u+2] = v[2]; w2l[4*u+3] = v[3];
  }
  const float b20 = b2[0], b21 = b2[1];

  // ---- prologue: stage W1 (chunk-deinterleaved) + set-0 x tiles (padded) ----
  #pragma unroll
  for (int r = 0; r < 8; ++r) {
    int s = r * NT + t;
    int k = s >> 5, gm = s & 31;
    int slot = ((gm & 1) << 4) | (gm >> 1);   // even chunks -> 0..15, odd -> 16..31
    *(f4*)&W1s[k * HN + slot * 4] = *(const f4*)(W1 + s * 4);
  }
  #pragma unroll
  for (int r = 0; r < 8; ++r) {
    int s = r * NT + t;
    int pp = s >> 10, q = s & 1023, n = q >> 5, pc = q & 31;
    *(f4*)&xs[pp * TILE + n * SX + pc * 4] =
        *(const f4*)(x + ((long)(g0 + pp) * NPG + n) * HN + pc * 4);
  }
  __syncthreads();

  for (int si = 0; si < spb; ++si) {
    const int  gs = g0 + si * GP4;
    const int  g  = gs + p;
    const long nb = (long)g * NPG;
    const bool more = (si + 1 < spb);

    // ---- R-A: prefetch next set's x tiles into regs; gn for this set ----
    f4 xr[8];
    if (more) {
      #pragma unroll
      for (int r = 0; r < 8; ++r) {
        int s = r * NT + t;
        int pp = s >> 10, q = s & 1023, n = q >> 5, pc = q & 31;
        xr[r] = *(const f4*)(x + ((long)(gs + GP4 + pp) * NPG + n) * HN + pc * 4);
      }
    }
    f2 gnr = {0.f, 0.f};
    if (wv < GP4 && lid < NPG)
      gnr = *(const f2*)(gn + ((long)(gs + wv) * NPG + lid) * 2);

    // ---- R-B1: stats partials (per feature-pair over 16 nodes) ----
    {
      const float* xb = &xs[p * TILE + half * 16 * SX + 2 * fp];
      float s10 = 0.f, s11 = 0.f, s20 = 0.f, s21 = 0.f;
      #pragma unroll
      for (int it = 0; it < 16; ++it) {
        f2 v = *(const f2*)(xb + it * SX);
        s10 += v[0]; s11 += v[1];
        s20 = fmaf(v[0], v[0], s20);
        s21 = fmaf(v[1], v[1], s21);
      }
      f2 w0 = {s10, s11}, w1v = {s20, s21};
      *(f2*)&pA[p][half][2 * fp] = w0;
      *(f2*)&pB[p][half][2 * fp] = w1v;
    }

    // ---- R-B2: MLP (4 nodes x 8 cols per thread), all LDS addrs immediate ----
    f4 aa[4], ab[4];
    #pragma unroll
    for (int i = 0; i < 4; ++i) { aa[i] = b1a; ab[i] = b1b; }
    {
      const float* xb = &xs[p * TILE + ng * SX];
      const float* wb = &W1s[cg * 4];
      #pragma unroll 8
      for (int pc = 0; pc < 32; ++pc) {
        f4 xv0 = *(const f4*)(xb + pc * 4);
        f4 xv1 = *(const f4*)(xb + 8  * SX + pc * 4);
        f4 xv2 = *(const f4*)(xb + 16 * SX + pc * 4);
        f4 xv3 = *(const f4*)(xb + 24 * SX + pc * 4);
        #pragma unroll
        for (int j = 0; j < 4; ++j) {
          f4 wa  = *(const f4*)(wb + (4 * pc + j) * HN);
          f4 wbv = *(const f4*)(wb + (4 * pc + j) * HN + 64);
          aa[0] += wa * xv0[j]; ab[0] += wbv * xv0[j];
          aa[1] += wa * xv1[j]; ab[1] += wbv * xv1[j];
          aa[2] += wa * xv2[j]; ab[2] += wbv * xv2[j];
          aa[3] += wa * xv3[j]; ab[3] += wbv * xv3[j];
        }
      }
    }
    #pragma unroll
    for (int i = 0; i < 4; ++i) {
      float z0 = 0.f, z1 = 0.f;
      #pragma unroll
      for (int u = 0; u < 4; ++u) {
        float h = tanhf(aa[i][u]);
        z0 = fmaf(h, w2l[2 * u], z0);
        z1 = fmaf(h, w2l[2 * u + 1], z1);
      }
      #pragma unroll
      for (int u = 0; u < 4; ++u) {
        float h = tanhf(ab[i][u]);
        z0 = fmaf(h, w2l[8 + 2 * u], z0);
        z1 = fmaf(h, w2l[9 + 2 * u], z1);
      }
      #pragma unroll
      for (int m = 8; m <= 32; m <<= 1) {
        z0 += __shfl_xor(z0, m, 64);
        z1 += __shfl_xor(z1, m, 64);
      }
      if (lid < 8) { zred[p][half][ng][i][0] = z0; zred[p][half][ng][i][1] = z1; }
    }
    __syncthreads();   // B1

    // ---- R-C: stats finalize + softmax/gumbel (waves 0..3 -> graph wv) ----
    if (wv < GP4) {
      const int gq = gs + wv;
      // stats finalize: 64 lanes, feature pair = lid
      f2 sa0 = *(const f2*)&pA[wv][0][2 * lid];
      f2 sa1 = *(const f2*)&pA[wv][1][2 * lid];
      f2 sb0 = *(const f2*)&pB[wv][0][2 * lid];
      f2 sb1 = *(const f2*)&pB[wv][1][2 * lid];
      float s10 = sa0[0] + sa1[0], s11 = sa0[1] + sa1[1];
      float s20 = sb0[0] + sb1[0], s21 = sb0[1] + sb1[1];
      float mean0 = s10 * (1.f / NPG), mean1 = s11 * (1.f / NPG);
      float var0 = fmaxf((s20 - s10 * mean0) * (1.f / (NPG - 1)), 0.f);
      float var1 = fmaxf((s21 - s11 * mean1) * (1.f / (NPG - 1)), 0.f);
      float sd0 = sqrtf(var0), sd1 = sqrtf(var1);
      float inv0 = 1.f / (sd0 + 1e-7f), inv1 = 1.f / (sd1 + 1e-7f);
      f2 mv = {mean0, mean1}, sv = {sd0, sd1}, iv = {inv0 * inv0, inv1 * inv1};
      *(f2*)&s_mean[wv][2 * lid] = mv;
      *(f2*)&s_std [wv][2 * lid] = sv;
      *(f2*)&s_iv  [wv][2 * lid] = iv;
      f2 ge = {s10, s11};
      *(f2*)&out[(long)gq * HN + 2 * lid] = ge;           // graph_emb
      float r0 = sd0 * inv0, r1 = sd1 * inv1;
      float r2 = r0 * r0 + r1 * r1;
      #pragma unroll
      for (int m = 1; m <= 32; m <<= 1) r2 += __shfl_xor(r2, m, 64);
      if (lid == 0) sr2p[wv] = r2;
      // softmax + gumbel: lanes 0..31 = nodes
      if (lid < NPG) {
        const int n = lid;
        float z0 = b20 + zred[wv][0][n & 7][n >> 3][0] + zred[wv][1][n & 7][n >> 3][0];
        float z1 = b21 + zred[wv][0][n & 7][n >> 3][1] + zred[wv][1][n & 7][n >> 3][1];
        float zm = fmaxf(z0, z1);
        float e0 = expf(z0 - zm), e1 = expf(z1 - zm);
        float a0 = e0 / (e0 + e1), a1 = 1.f - a0;
        float q0 = a0 + gnr[0], q1 = a1 + gnr[1];
        float qm = fmaxf(q0, q1);
        float E0 = expf(q0 - qm), E1 = expf(q1 - qm);
        float lp = E0 / (E0 + E1), ln = 1.f - lp;
        s_a0[wv][n] = a0; s_a1[wv][n] = a1; s_lp[wv][n] = lp; s_ln[wv][n] = ln;
        out[2 * GL + (long)gq * NPG + n] = (lp > 0.5f) ? 1.0f : 0.0f;   // active
        float v1 = ln, v2 = ln * ln, v3 = (a0 > 0.5f) ? 1.f : 0.f;
        #pragma unroll
        for (int m = 1; m <= 16; m <<= 1) {
          v1 += __shfl_xor(v1, m, 64);
          v2 += __shfl_xor(v2, m, 64);
          v3 += __shfl_xor(v3, m, 64);
        }
        if (n == 0) { s_scal[wv][0] = v1; s_scal[wv][1] = v2; s_scal[wv][2] = v3; }
      }
    }
    __syncthreads();   // B2

    // ---- R-D: T2 + noisy partials (fused) + edges ----
    {
      // issue global loads first
      f2 ur[16];
      #pragma unroll
      for (int it = 0; it < 16; ++it)
        ur[it] = *(const f2*)(un + (nb + half * 16 + it) * HN + 2 * fp);
      int es = 0, ed = 0;
      if (lo < epg) {
        es = ei[(long)g * epg + lo] - g * NPG;
        ed = ei[E + (long)g * epg + lo] - g * NPG;
      }
      // fused T2 + noisy partial loop
      const float* xb = &xs[p * TILE + half * 16 * SX + 2 * fp];
      f2 mu = *(const f2*)&s_mean[p][2 * fp];
      f2 iv = *(const f2*)&s_iv[p][2 * fp];
      float tv = 0.f, A0 = 0.f, A1 = 0.f, B0 = 0.f, B1 = 0.f;
      #pragma unroll
      for (int it = 0; it < 16; ++it) {
        const int n = half * 16 + it;
        f2 v = *(const f2*)(xb + it * SX);
        float lpn = s_lp[p][n], lnn = s_ln[p][n];
        float d0 = v[0] - mu[0], d1 = v[1] - mu[1];
        tv = fmaf(lpn * lpn, fmaf(d0 * d0, iv[0], d1 * d1 * iv[1]), tv);
        A0 = fmaf(lpn, v[0], A0); A1 = fmaf(lpn, v[1], A1);
        B0 = fmaf(lnn, ur[it][0], B0); B1 = fmaf(lnn, ur[it][1], B1);
      }
      #pragma unroll
      for (int m = 1; m <= 32; m <<= 1) tv += __shfl_xor(tv, m, 64);
      if (lid == 0) t2p[p][half] = tv;
      f2 wA = {A0, A1}, wB = {B0, B1};
      *(f2*)&pA[p][half][2 * fp] = wA;
      *(f2*)&pB[p][half][2 * fp] = wB;
      // edges
      float c00 = 0.f, c01 = 0.f, c10 = 0.f, c11 = 0.f;
      if (lo < epg) {
        float as0 = s_a0[p][es], as1 = s_a1[p][es];
        float ad0 = s_a0[p][ed], ad1 = s_a1[p][ed];
        c00 = as0 * ad0; c01 = as0 * ad1; c10 = as1 * ad0; c11 = as1 * ad1;
      }
      for (int e = 128 + lo; e < epg; e += 128) {
        int s2 = ei[(long)g * epg + e] - g * NPG;
        int d2 = ei[E + (long)g * epg + e] - g * NPG;
        float as0 = s_a0[p][s2], as1 = s_a1[p][s2];
        float ad0 = s_a0[p][d2], ad1 = s_a1[p][d2];
        c00 = fmaf(as0, ad0, c00); c01 = fmaf(as0, ad1, c01);
        c10 = fmaf(as1, ad0, c10); c11 = fmaf(as1, ad1, c11);
      }
      #pragma unroll
      for (int m = 1; m <= 32; m <<= 1) {
        c00 += __shfl_xor(c00, m, 64); c01 += __shfl_xor(c01, m, 64);
        c10 += __shfl_xor(c10, m, 64); c11 += __shfl_xor(c11, m, 64);
      }
      if (lid == 0) {
        adjp[p][half][0] = c00; adjp[p][half][1] = c01;
        adjp[p][half][2] = c10; adjp[p][half][3] = c11;
      }
    }
    __syncthreads();   // B3

    // ---- R-E: finalize noisy + scalars (waves 0..3); stage next tiles (all) ----
    if (wv < GP4) {
      const int gq = gs + wv;
      f2 a0v = *(const f2*)&pA[wv][0][2 * lid];
      f2 a1v = *(const f2*)&pA[wv][1][2 * lid];
      f2 b0v = *(const f2*)&pB[wv][0][2 * lid];
      f2 b1v2 = *(const f2*)&pB[wv][1][2 * lid];
      f2 mu = *(const f2*)&s_mean[wv][2 * lid];
      f2 sd = *(const f2*)&s_std[wv][2 * lid];
      float SLN = s_scal[wv][0];
      f2 ne;
      ne[0] = fmaf(mu[0], SLN, a0v[0] + a1v[0]) + sd[0] * (b0v[0] + b1v2[0]);
      ne[1] = fmaf(mu[1], SLN, a0v[1] + a1v[1]) + sd[1] * (b0v[1] + b1v2[1]);
      *(f2*)&out[GL + (long)gq * HN + 2 * lid] = ne;      // noisy_emb
      if (lid == 32) {
        float a00 = adjp[wv][0][0] + adjp[wv][1][0];
        float a01 = adjp[wv][0][1] + adjp[wv][1][1];
        float a10 = adjp[wv][0][2] + adjp[wv][1][2];
        float a11 = adjp[wv][0][3] + adjp[wv][1][3];
        float d0 = a00 / fmaxf(fabsf(a00) + fabsf(a01), 1e-12f);
        float d1 = a11 / fmaxf(fabsf(a10) + fabsf(a11), 1e-12f);
        float pen = 0.5f * ((d0 - 1.f) * (d0 - 1.f) + (d1 - 1.f) * (d1 - 1.f));
        float t2 = t2p[wv][0] + t2p[wv][1];
        float kl = (0.5f * s_scal[wv][1] * sr2p[wv] + (float)NPG * t2) / (float)(NPG * HN);
        ws[gq]                 = kl;
        ws[(size_t)G + gq]     = pen;
        ws[2 * (size_t)G + gq] = s_scal[wv][2] * (1.0f / NPG);
      }
    }
    if (more) {
      #pragma unroll
      for (int r = 0; r < 8; ++r) {
        int s = r * NT + t;
        int pp = s >> 10, q = s & 1023, n = q >> 5, pc = q & 31;
        *(f4*)&xs[pp * TILE + n * SX + pc * 4] = xr[r];
      }
    }
    __syncthreads();   // B4
  }
}

// deterministic fixed-order reduction of the 3 per-graph scalar arrays
__global__ __launch_bounds__(1024) void gib_final(const float* __restrict__ ws,
                                                  float* __restrict__ out,
                                                  int G, long base)
{
  __shared__ float red[3][16];
  const int t = threadIdx.x, w = t >> 6, lid = t & 63;
  float s0 = 0.f, s1 = 0.f, s2 = 0.f;
  for (int i = t; i < G; i += 1024) {
    s0 += ws[(size_t)G + i];       // pos_penalty
    s1 += ws[i];                   // kl
    s2 += ws[2 * (size_t)G + i];   // preserve
  }
  #pragma unroll
  for (int m = 1; m <= 32; m <<= 1) {
    s0 += __shfl_xor(s0, m, 64);
    s1 += __shfl_xor(s1, m, 64);
    s2 += __shfl_xor(s2, m, 64);
  }
  if (lid == 0) { red[0][w] = s0; red[1][w] = s1; red[2][w] = s2; }
  __syncthreads();
  if (t == 0) {
    float r0 = 0.f, r1 = 0.f, r2 = 0.f;
    for (int i = 0; i < 16; ++i) { r0 += red[0][i]; r1 += red[1][i]; r2 += red[2][i]; }
    out[base + 0] = r0 / (float)G;
    out[base + 1] = r1 / (float)G;
    out[base + 2] = r2 / (float)G;
  }
}

extern "C" void kernel_launch(void* const* d_in, const int* in_sizes, int n_in,
                              void* d_out, int out_size, void* d_ws, size_t ws_size,
                              hipStream_t stream)
{
  const float* x  = (const float*)d_in[0];
  const float* W1 = (const float*)d_in[1];
  const float* b1 = (const float*)d_in[2];
  const float* W2 = (const float*)d_in[3];
  const float* b2 = (const float*)d_in[4];
  const float* gn = (const float*)d_in[5];
  const float* un = (const float*)d_in[6];
  const int*   ei = (const int*)d_in[7];
  float* out = (float*)d_out;
  float* ws  = (float*)d_ws;

  const long N = (long)in_sizes[0] / HN;
  const int  G = (int)(N / NPG);
  const long E = (long)in_sizes[7] / 2;
  const int epg = (int)(E / G);

  const int spb = 8;                         // sets per block
  const int nblocks = G / (GP4 * spb);       // 32768/32 = 1024
  hipLaunchKernelGGL(gib_main, dim3(nblocks), dim3(NT), 0, stream,
                     x, W1, b1, W2, b2, gn, un, ei, out, ws, G, E, epg, spb);
  const long base = 2L * (long)G * HN + N;
  hipLaunchKernelGGL(gib_final, dim3(1), dim3(1024), 0, stream, ws, out, G, base);
}